// Round 8
// baseline (122.054 us; speedup 1.0000x reference)
//
#include <hip/hip_runtime.h>
#include <math.h>

// EEG_Deformer — target: jax-CPU XLA f32 reference.
// Model (calibrated via rounds 1-7 flip forensics):
//   R6(f64-CR tanh) == R7(ocml tanhf) bit-identical absmax 1.0283 =>
//   reference tanh deviates >1ulp from CR at flip points => rational approx
//   => XLA EmitFastTanh. R5 rejected the no-FMA variant (2.21), so target the
//   WITH-FMA variant (host CPU has FMA): clamp ±7.99881172180175781,
//   Horner chains as true fma; numerator = x*P, denominator Q, r = num/q,
//   |s|<0.0004 passthrough.
//   conv: XLA-CPU -> Eigen im2col GEMM: TRUE-FMA chain, ascending taps, acc=0.
//   bias add, *5, pos adds (((off+t)+n)+7), lr/rr, lr*v+rr*v, sum_k: all
//   separate unfused f32 ops (XLA emits no contraction by default).
// #pragma clang fp contract(off) is load-bearing: hipcc fuses mul+add across
// statements by default; explicit __builtin_fmaf marks intended fusions only.

constexpr int KK   = 5;
constexpr int TT   = 4000;
constexpr int HEAD = 7;                 // K//2 + L
constexpr int TAIL = 7;                 // (K-1)//2 + L
constexpr int TEXT = TT + HEAD + TAIL;  // 4014
constexpr int BLK  = 256;

// XLA EmitFastTanh, with_fma = true.
__device__ __forceinline__ float xla_tanh_fma(float s) {
#pragma clang fp contract(off)
    const float clampv = 7.99881172180175781f;
    float x  = fminf(fmaxf(s, -clampv), clampv);
    float x2 = x * x;                                  // plain mul
    // numerator = x * P(x2), Horner with TRUE fma
    float p = -2.76076847742355e-16f;                  // a13
    p = __builtin_fmaf(x2, p, 2.00018790482477e-13f);  // a11
    p = __builtin_fmaf(x2, p, -8.60467152213735e-11f); // a9
    p = __builtin_fmaf(x2, p, 5.12229709037114e-08f);  // a7
    p = __builtin_fmaf(x2, p, 1.48572235717979e-05f);  // a5
    p = __builtin_fmaf(x2, p, 6.37261928875436e-04f);  // a3
    p = __builtin_fmaf(x2, p, 4.89352455891786e-03f);  // a1
    float num = x * p;                                 // plain mul
    // denominator Q(x2), Horner with TRUE fma
    float q = 1.19825839466702e-06f;                   // b6
    q = __builtin_fmaf(x2, q, 1.18534705686654e-04f);  // b4
    q = __builtin_fmaf(x2, q, 2.26843463243900e-03f);  // b2
    q = __builtin_fmaf(x2, q, 4.89352518554385e-03f);  // b0
    float r = num / q;                                 // IEEE div (default precise)
    return (fabsf(s) < 0.0004f) ? s : r;               // passthrough on pre-clamp s
}

__global__ __launch_bounds__(BLK) void eeg_deform_kernel(
    const float* __restrict__ x,
    const float* __restrict__ w_off,
    const float* __restrict__ b_off,
    float* __restrict__ out)
{
#pragma clang fp contract(off)
    __shared__ float xe[TEXT];   // x_ext for this row

    const int row = blockIdx.x;                    // b*C + c
    const float* __restrict__ xr = x + (size_t)row * TT;
    float* __restrict__ outr      = out + (size_t)row * TT;
    const int tid = threadIdx.x;

    // ---- stage row into LDS as x_ext (vectorized float4)
    const float4* __restrict__ xr4 = reinterpret_cast<const float4*>(xr);
    for (int i = tid; i < TT / 4; i += BLK) {
        float4 v = xr4[i];
        xe[HEAD + 4 * i + 0] = v.x;
        xe[HEAD + 4 * i + 1] = v.y;
        xe[HEAD + 4 * i + 2] = v.z;
        xe[HEAD + 4 * i + 3] = v.w;
    }
    if (tid < HEAD) {
        xe[tid] = xr[TT - TAIL + tid];             // wrap: last 7 of x
    } else if (tid >= BLK - TAIL) {
        int j = tid - (BLK - TAIL);
        xe[HEAD + TT + j] = xr[j];                 // wrap: first 7 of x
    }

    // ---- weights/bias into registers (uniform -> scalar loads)
    float w[KK][KK];
    float bv[KK];
#pragma unroll
    for (int k = 0; k < KK; ++k) {
        bv[k] = b_off[k];
#pragma unroll
        for (int j = 0; j < KK; ++j) w[k][j] = w_off[k * KK + j];
    }

    __syncthreads();

    // ---- main loop: each thread strides over t
    for (int t = tid; t < TT; t += BLK) {
        const float tf = (float)t;
        float acc = 0.0f;
#pragma unroll
        for (int k = 0; k < KK; ++k) {
            // conv: Eigen-style TRUE fma chain, ascending j, acc from 0
            float s = 0.0f;
#pragma unroll
            for (int j = 0; j < KK; ++j) {
                const int u = t + j - 2;
                const float xv = (u >= 0 && u < TT) ? xe[HEAD + u] : 0.0f;
                s = __builtin_fmaf(xv, w[k][j], s);
            }
            s = s + bv[k];                         // bias: separate unfused add

            const float th = xla_tanh_fma(s);

            const float off = th * 5.0f;           // * L, unfused
            // ((off + t) + n) + 7, each add rounded separately
            float pos = off + tf;
            pos = pos + (float)(k - 2);
            pos = pos + 7.0f;
            const float left = floorf(pos);
            const float lr   = pos - left;
            const float rr   = (left + 1.0f) - pos;
            int idx = (int)left;                   // in [0, T+13] by construction
            idx = idx < 0 ? 0 : (idx > TEXT - 1 ? TEXT - 1 : idx);
            const float v = xe[idx];
            const float term = lr * v + rr * v;    // unfused
            acc = acc + term;                      // ascending k from 0
        }
        outr[t] = acc;
    }
}

extern "C" void kernel_launch(void* const* d_in, const int* in_sizes, int n_in,
                              void* d_out, int out_size, void* d_ws, size_t ws_size,
                              hipStream_t stream) {
    const float* x     = (const float*)d_in[0];
    const float* w_off = (const float*)d_in[1];
    const float* b_off = (const float*)d_in[2];
    float* out         = (float*)d_out;

    const int rows = in_sizes[0] / TT;             // B*C = 2048
    eeg_deform_kernel<<<rows, BLK, 0, stream>>>(x, w_off, b_off, out);
}

// Round 9
// 116.559 us; speedup vs baseline: 1.0471x; 1.0471x over previous
//
#include <hip/hip_runtime.h>
#include <math.h>

// EEG_Deformer — bit-faithful to jax-CPU XLA f32 (confirmed PASS in R8).
//   tanh: XLA EmitFastTanh with_fma (clamp ±7.99881172180175781), IEEE div.
//   conv: Eigen true-FMA chain, ascending taps, acc from 0.
//   pos = ((off + t) + n) + 7, unfused adds (contract(off) pragma).
// Perf cuts vs R8 (all proven output-safe at the 0.35 absmax threshold):
//   - out = sum_k v_k   (lr*v + rr*v == v to ~1.5 ulp; only floor(pos) matters)
//   - no idx clamp:   pos in [t, t+14] subset [0, 4013] by |tanh|<=1 proof
//   - (int)pos == floor for pos>=0 -> no floorf
//   - conv zero-pad guards only on boundary t (t<2 or t>=3998)

constexpr int KK   = 5;
constexpr int TT   = 4000;
constexpr int HEAD = 7;                 // K//2 + L
constexpr int TAIL = 7;                 // (K-1)//2 + L
constexpr int TEXT = TT + HEAD + TAIL;  // 4014
constexpr int BLK  = 256;

// XLA EmitFastTanh, with_fma = true. BIT-EXACTNESS CONTRACT — do not alter.
__device__ __forceinline__ float xla_tanh_fma(float s) {
#pragma clang fp contract(off)
    const float clampv = 7.99881172180175781f;
    float x  = fminf(fmaxf(s, -clampv), clampv);
    float x2 = x * x;                                  // plain mul
    float p = -2.76076847742355e-16f;                  // a13
    p = __builtin_fmaf(x2, p, 2.00018790482477e-13f);  // a11
    p = __builtin_fmaf(x2, p, -8.60467152213735e-11f); // a9
    p = __builtin_fmaf(x2, p, 5.12229709037114e-08f);  // a7
    p = __builtin_fmaf(x2, p, 1.48572235717979e-05f);  // a5
    p = __builtin_fmaf(x2, p, 6.37261928875436e-04f);  // a3
    p = __builtin_fmaf(x2, p, 4.89352455891786e-03f);  // a1
    float num = x * p;                                 // plain mul
    float q = 1.19825839466702e-06f;                   // b6
    q = __builtin_fmaf(x2, q, 1.18534705686654e-04f);  // b4
    q = __builtin_fmaf(x2, q, 2.26843463243900e-03f);  // b2
    q = __builtin_fmaf(x2, q, 4.89352518554385e-03f);  // b0
    float r = num / q;                                 // IEEE-precise div
    return (fabsf(s) < 0.0004f) ? s : r;               // passthrough on pre-clamp s
}

__global__ __launch_bounds__(BLK) void eeg_deform_kernel(
    const float* __restrict__ x,
    const float* __restrict__ w_off,
    const float* __restrict__ b_off,
    float* __restrict__ out)
{
#pragma clang fp contract(off)
    __shared__ float xe[TEXT];   // x_ext for this row

    const int row = blockIdx.x;                    // b*C + c
    const float* __restrict__ xr = x + (size_t)row * TT;
    float* __restrict__ outr      = out + (size_t)row * TT;
    const int tid = threadIdx.x;

    // ---- stage row into LDS as x_ext (vectorized float4)
    const float4* __restrict__ xr4 = reinterpret_cast<const float4*>(xr);
    for (int i = tid; i < TT / 4; i += BLK) {
        float4 v = xr4[i];
        xe[HEAD + 4 * i + 0] = v.x;
        xe[HEAD + 4 * i + 1] = v.y;
        xe[HEAD + 4 * i + 2] = v.z;
        xe[HEAD + 4 * i + 3] = v.w;
    }
    if (tid < HEAD) {
        xe[tid] = xr[TT - TAIL + tid];             // wrap: last 7 of x
    } else if (tid >= BLK - TAIL) {
        int j = tid - (BLK - TAIL);
        xe[HEAD + TT + j] = xr[j];                 // wrap: first 7 of x
    }

    // ---- weights/bias into registers (uniform -> scalar loads)
    float w[KK][KK];
    float bv[KK];
#pragma unroll
    for (int k = 0; k < KK; ++k) {
        bv[k] = b_off[k];
#pragma unroll
        for (int j = 0; j < KK; ++j) w[k][j] = w_off[k * KK + j];
    }

    __syncthreads();

    // ---- main loop: each thread strides over t
    for (int t = tid; t < TT; t += BLK) {
        const float tf = (float)t;

        // conv window, hoisted across k; guards only on boundary t
        float xv[KK];
        if (t >= 2 && t < TT - 2) {
#pragma unroll
            for (int j = 0; j < KK; ++j) xv[j] = xe[HEAD + t + j - 2];
        } else {
#pragma unroll
            for (int j = 0; j < KK; ++j) {
                const int u = t + j - 2;
                xv[j] = (u >= 0 && u < TT) ? xe[HEAD + u] : 0.0f;
            }
        }

        float acc = 0.0f;
#pragma unroll
        for (int k = 0; k < KK; ++k) {
            // conv: Eigen true-FMA chain, ascending j, acc from 0 (bit-exact)
            float s = 0.0f;
#pragma unroll
            for (int j = 0; j < KK; ++j) s = __builtin_fmaf(xv[j], w[k][j], s);
            s = s + bv[k];                         // bias: separate unfused add

            const float th = xla_tanh_fma(s);

            const float off = th * 5.0f;           // unfused (pragma)
            // ((off + t) + n) + 7, each add rounded separately — floor contract
            float pos = off + tf;
            pos = pos + (float)(k - 2);
            pos = pos + 7.0f;
            // pos in [t, t+14] ⊆ [0, 4013]; (int) truncation == floor for >=0
            const int idx = (int)pos;
            acc = acc + xe[idx];                   // lr*v + rr*v == v (±1.5 ulp)
        }
        outr[t] = acc;
    }
}

extern "C" void kernel_launch(void* const* d_in, const int* in_sizes, int n_in,
                              void* d_out, int out_size, void* d_ws, size_t ws_size,
                              hipStream_t stream) {
    const float* x     = (const float*)d_in[0];
    const float* w_off = (const float*)d_in[1];
    const float* b_off = (const float*)d_in[2];
    float* out         = (float*)d_out;

    const int rows = in_sizes[0] / TT;             // B*C = 2048
    eeg_deform_kernel<<<rows, BLK, 0, stream>>>(x, w_off, b_off, out);
}

// Round 10
// 110.366 us; speedup vs baseline: 1.1059x; 1.0561x over previous
//
#include <hip/hip_runtime.h>
#include <math.h>

// EEG_Deformer — bit-faithful to jax-CPU XLA f32 (PASS R8/R9, absmax 0.03125).
// Bit-exactness contract (do not alter):
//   tanh: XLA EmitFastTanh with_fma (clamp ±7.99881172180175781)
//   conv: Eigen true-FMA chain, ascending taps, acc from 0; bias separate add
//   pos = ((off + t) + n) + 7, unfused adds; only floor(pos) reaches output
// Perf (R10): outer unroll x2 (ILP for the serial tanh+gather chains;
// VALUBusy was 68%) + guarded fast division: th = num*v_rcp(q), exact IEEE
// div fallback only when pos is within 1e-3 of an integer (fast-vs-exact pos
// differ <= 1 ulp <= 2.44e-4, so the guard provably preserves every floor).

constexpr int KK   = 5;
constexpr int TT   = 4000;
constexpr int HEAD = 7;                 // K//2 + L
constexpr int TAIL = 7;                 // (K-1)//2 + L
constexpr int TEXT = TT + HEAD + TAIL;  // 4014
constexpr int BLK  = 256;

__device__ __forceinline__ float proc1(const float* __restrict__ xe,
                                       const float (&w)[KK][KK],
                                       const float (&bv)[KK],
                                       int t)
{
#pragma clang fp contract(off)
    const float tf = (float)t;

    float xv[KK];
    if (t >= 2 && t < TT - 2) {
#pragma unroll
        for (int j = 0; j < KK; ++j) xv[j] = xe[HEAD + t + j - 2];
    } else {
#pragma unroll
        for (int j = 0; j < KK; ++j) {
            const int u = t + j - 2;
            xv[j] = (u >= 0 && u < TT) ? xe[HEAD + u] : 0.0f;
        }
    }

    float acc = 0.0f;
#pragma unroll
    for (int k = 0; k < KK; ++k) {
        // conv: Eigen true-FMA chain, ascending j, acc from 0 (bit-exact)
        float s = 0.0f;
#pragma unroll
        for (int j = 0; j < KK; ++j) s = __builtin_fmaf(xv[j], w[k][j], s);
        s = s + bv[k];                         // bias: separate unfused add

        // XLA EmitFastTanh with_fma — polynomial part (bit-exact)
        const float clampv = 7.99881172180175781f;
        const float xx = fminf(fmaxf(s, -clampv), clampv);
        const float x2 = xx * xx;                              // plain mul
        float p = -2.76076847742355e-16f;                      // a13
        p = __builtin_fmaf(x2, p, 2.00018790482477e-13f);      // a11
        p = __builtin_fmaf(x2, p, -8.60467152213735e-11f);     // a9
        p = __builtin_fmaf(x2, p, 5.12229709037114e-08f);      // a7
        p = __builtin_fmaf(x2, p, 1.48572235717979e-05f);      // a5
        p = __builtin_fmaf(x2, p, 6.37261928875436e-04f);      // a3
        p = __builtin_fmaf(x2, p, 4.89352455891786e-03f);      // a1
        const float num = xx * p;                              // plain mul
        float q = 1.19825839466702e-06f;                       // b6
        q = __builtin_fmaf(x2, q, 1.18534705686654e-04f);      // b4
        q = __builtin_fmaf(x2, q, 2.26843463243900e-03f);      // b2
        q = __builtin_fmaf(x2, q, 4.89352518554385e-03f);      // b0

        // fast path: hardware rcp (<=1 ulp) instead of IEEE div expansion
        float th = num * __builtin_amdgcn_rcpf(q);
        if (fabsf(s) < 0.0004f) th = s;                        // passthrough
        float off = th * 5.0f;
        float pos = off + tf;                                  // unfused chain
        pos = pos + (float)(k - 2);
        pos = pos + 7.0f;

        // guard: if pos within 1e-3 of an integer, redo with exact IEEE div.
        // fast-vs-exact pos differ by <= 1 ulp (<= 2.44e-4) -> guard provably
        // catches every possible floor discrepancy (4x margin).
        const float dd = pos - rintf(pos);
        if (fabsf(dd) < 1e-3f) {
            float thx = num / q;                               // IEEE-precise div
            if (fabsf(s) < 0.0004f) thx = s;
            float offx = thx * 5.0f;
            float posx = offx + tf;
            posx = posx + (float)(k - 2);
            posx = posx + 7.0f;
            pos = posx;
        }

        // pos in [t, t+14] ⊆ [0, 4013]; (int) truncation == floor for >= 0
        const int idx = (int)pos;
        acc = acc + xe[idx];                   // lr*v + rr*v == v (±1.5 ulp)
    }
    return acc;
}

__global__ __launch_bounds__(BLK) void eeg_deform_kernel(
    const float* __restrict__ x,
    const float* __restrict__ w_off,
    const float* __restrict__ b_off,
    float* __restrict__ out)
{
#pragma clang fp contract(off)
    __shared__ float xe[TEXT];   // x_ext for this row

    const int row = blockIdx.x;                    // b*C + c
    const float* __restrict__ xr = x + (size_t)row * TT;
    float* __restrict__ outr      = out + (size_t)row * TT;
    const int tid = threadIdx.x;

    // ---- stage row into LDS as x_ext (vectorized float4)
    const float4* __restrict__ xr4 = reinterpret_cast<const float4*>(xr);
    for (int i = tid; i < TT / 4; i += BLK) {
        float4 v = xr4[i];
        xe[HEAD + 4 * i + 0] = v.x;
        xe[HEAD + 4 * i + 1] = v.y;
        xe[HEAD + 4 * i + 2] = v.z;
        xe[HEAD + 4 * i + 3] = v.w;
    }
    if (tid < HEAD) {
        xe[tid] = xr[TT - TAIL + tid];             // wrap: last 7 of x
    } else if (tid >= BLK - TAIL) {
        int j = tid - (BLK - TAIL);
        xe[HEAD + TT + j] = xr[j];                 // wrap: first 7 of x
    }

    // ---- weights/bias into registers (uniform -> scalar loads)
    float w[KK][KK];
    float bv[KK];
#pragma unroll
    for (int k = 0; k < KK; ++k) {
        bv[k] = b_off[k];
#pragma unroll
        for (int j = 0; j < KK; ++j) w[k][j] = w_off[k * KK + j];
    }

    __syncthreads();

    // ---- main loop: unroll x2 across t (independent pipelines -> ILP)
    int t = tid;
    for (; t + BLK < TT; t += 2 * BLK) {
        const float a0 = proc1(xe, w, bv, t);
        const float a1 = proc1(xe, w, bv, t + BLK);
        outr[t]       = a0;
        outr[t + BLK] = a1;
    }
    for (; t < TT; t += BLK) {
        outr[t] = proc1(xe, w, bv, t);
    }
}

extern "C" void kernel_launch(void* const* d_in, const int* in_sizes, int n_in,
                              void* d_out, int out_size, void* d_ws, size_t ws_size,
                              hipStream_t stream) {
    const float* x     = (const float*)d_in[0];
    const float* w_off = (const float*)d_in[1];
    const float* b_off = (const float*)d_in[2];
    float* out         = (float*)d_out;

    const int rows = in_sizes[0] / TT;             // B*C = 2048
    eeg_deform_kernel<<<rows, BLK, 0, stream>>>(x, w_off, b_off, out);
}